// Round 1
// baseline (462.574 us; speedup 1.0000x reference)
//
#include <hip/hip_runtime.h>
#include <math.h>

#define B_ 4
#define D_ 256
#define N_ 2048
#define H_ 4
#define HD_ 64

// ---------------------------------------------------------------------------
// conv1x1 GEMM: out[b,o,n] = act( sum_i W[o,i] * in[b,i,n] + bias[o] )
// in = concat(in1 [C1 channels], in2 [C2 channels]) along channel dim.
// Tile: 64 (o) x 64 (n), 256 threads, 4x4 microtile, K-step 16.
// ---------------------------------------------------------------------------
template <int RELU>
__global__ __launch_bounds__(256) void conv1x1_kernel(
    const float* __restrict__ in1, int C1,
    const float* __restrict__ in2, int C2,
    const float* __restrict__ W, const float* __restrict__ bias,
    float* __restrict__ out, int Cout, int K)
{
    const int n0 = blockIdx.x * 64;
    const int o0 = blockIdx.y * 64;
    const int b  = blockIdx.z;
    const int t  = threadIdx.x;
    const int tr = t >> 4;   // 0..15 -> o micro-row
    const int tc = t & 15;   // 0..15 -> n micro-col

    __shared__ float sW[16][68];  // [k][o]
    __shared__ float sX[16][68];  // [k][n]

    float acc[4][4];
#pragma unroll
    for (int i = 0; i < 4; ++i)
#pragma unroll
        for (int j = 0; j < 4; ++j) acc[i][j] = 0.f;

    const int xrow = t >> 4;          // k row for X load
    const int xcol = (t & 15) * 4;    // n within tile
    const int wo   = t & 63;          // o for W load
    const int wk   = (t >> 6) * 4;    // k group for W load

    for (int k0 = 0; k0 < K; k0 += 16) {
        __syncthreads();
        // X tile: rows k0..k0+15, 64 n columns
        {
            const int ch = k0 + xrow;
            const float* src;
            if (ch < C1) src = in1 + ((size_t)b * C1 + ch) * N_ + n0 + xcol;
            else         src = in2 + ((size_t)b * C2 + (ch - C1)) * N_ + n0 + xcol;
            const float4 v = *(const float4*)src;
            *(float4*)&sX[xrow][xcol] = v;
        }
        // W tile: W[o0+wo][k0+wk..+3] -> sW[k][o] (transposed)
        {
            const float4 w = *(const float4*)&W[(size_t)(o0 + wo) * K + k0 + wk];
            sW[wk + 0][wo] = w.x;
            sW[wk + 1][wo] = w.y;
            sW[wk + 2][wo] = w.z;
            sW[wk + 3][wo] = w.w;
        }
        __syncthreads();
#pragma unroll
        for (int k = 0; k < 16; ++k) {
            const float4 wv = *(const float4*)&sW[k][tr * 4];
            const float4 xv = *(const float4*)&sX[k][tc * 4];
            const float wa[4] = {wv.x, wv.y, wv.z, wv.w};
            const float xa[4] = {xv.x, xv.y, xv.z, xv.w};
#pragma unroll
            for (int i = 0; i < 4; ++i)
#pragma unroll
                for (int j = 0; j < 4; ++j)
                    acc[i][j] = fmaf(wa[i], xa[j], acc[i][j]);
        }
    }

#pragma unroll
    for (int i = 0; i < 4; ++i) {
        const int o = o0 + tr * 4 + i;
        const float bs = bias[o];
        float4 r;
        r.x = acc[i][0] + bs;
        r.y = acc[i][1] + bs;
        r.z = acc[i][2] + bs;
        r.w = acc[i][3] + bs;
        if (RELU) {
            r.x = fmaxf(r.x, 0.f); r.y = fmaxf(r.y, 0.f);
            r.z = fmaxf(r.z, 0.f); r.w = fmaxf(r.w, 0.f);
        }
        *(float4*)&out[((size_t)b * Cout + o) * N_ + n0 + tc * 4] = r;
    }
}

// ---------------------------------------------------------------------------
// Fused flash-style attention per (b, h): 64 q-rows per block, m-tiles of 64.
// q/k/v stored as [B, D, N] with channel c = d*H + h (torch .view split).
// prob = softmax(scores) * edge  =>  numerator gets edge, denominator doesn't.
// msg[d][n] = (sum_m exp(s-M)*edge*v) / (sum_m exp(s-M))
// ---------------------------------------------------------------------------
__global__ __launch_bounds__(256) void attn_kernel(
    const float* __restrict__ Q, const float* __restrict__ Kt,
    const float* __restrict__ V, const float* __restrict__ edge,
    float* __restrict__ msg)
{
    const int n0 = blockIdx.x * 64;
    const int h  = blockIdx.y;
    const int b  = blockIdx.z;
    const int t  = threadIdx.x;
    const int sr = t >> 4;   // 0..15
    const int sc = t & 15;   // 0..15

    __shared__ float sQ[64][68];   // [d][n]
    __shared__ float sK[64][68];   // [d][m]
    __shared__ float sVT[64][68];  // [m][d]
    __shared__ float sPT[64][68];  // [m][n]
    __shared__ float sM[64], sL[64], sF[64];

    // load Q tile
    {
        const int seg = t & 15;
        const int dbase = t >> 4;
#pragma unroll
        for (int dd = 0; dd < 4; ++dd) {
            const int d = dd * 16 + dbase;
            const float4 v = *(const float4*)&Q[((size_t)b * D_ + d * H_ + h) * N_ + n0 + seg * 4];
            *(float4*)&sQ[d][seg * 4] = v;
        }
    }
    if (t < 64) { sM[t] = -3.0e38f; sL[t] = 0.f; }

    float acc[4][4];  // [i over d][j over n]
#pragma unroll
    for (int i = 0; i < 4; ++i)
#pragma unroll
        for (int j = 0; j < 4; ++j) acc[i][j] = 0.f;

    for (int mt = 0; mt < N_ / 64; ++mt) {
        const int m0 = mt * 64;
        __syncthreads();
        // load K tile [d][m] and V tile transposed [m][d]
        {
            const int seg = t & 15;
            const int dbase = t >> 4;
#pragma unroll
            for (int dd = 0; dd < 4; ++dd) {
                const int d = dd * 16 + dbase;
                const size_t off = ((size_t)b * D_ + d * H_ + h) * N_ + m0 + seg * 4;
                const float4 kv = *(const float4*)&Kt[off];
                *(float4*)&sK[d][seg * 4] = kv;
                const float4 vv = *(const float4*)&V[off];
                sVT[seg * 4 + 0][d] = vv.x;
                sVT[seg * 4 + 1][d] = vv.y;
                sVT[seg * 4 + 2][d] = vv.z;
                sVT[seg * 4 + 3][d] = vv.w;
            }
        }
        __syncthreads();

        // S = Q^T K : thread handles n = sr*4+j, m = sc*4+i
        float s[4][4];
#pragma unroll
        for (int j = 0; j < 4; ++j)
#pragma unroll
            for (int i = 0; i < 4; ++i) s[j][i] = 0.f;
        for (int d = 0; d < 64; ++d) {
            const float4 qv = *(const float4*)&sQ[d][sr * 4];
            const float4 kv = *(const float4*)&sK[d][sc * 4];
            const float qa[4] = {qv.x, qv.y, qv.z, qv.w};
            const float ka[4] = {kv.x, kv.y, kv.z, kv.w};
#pragma unroll
            for (int j = 0; j < 4; ++j)
#pragma unroll
                for (int i = 0; i < 4; ++i)
                    s[j][i] = fmaf(qa[j], ka[i], s[j][i]);
        }
#pragma unroll
        for (int j = 0; j < 4; ++j)
#pragma unroll
            for (int i = 0; i < 4; ++i) s[j][i] *= 0.125f;

        // per-row max over this tile (butterfly across the 16 sc lanes)
        float rm[4];
#pragma unroll
        for (int j = 0; j < 4; ++j)
            rm[j] = fmaxf(fmaxf(s[j][0], s[j][1]), fmaxf(s[j][2], s[j][3]));
#pragma unroll
        for (int mask = 1; mask < 16; mask <<= 1)
#pragma unroll
            for (int j = 0; j < 4; ++j)
                rm[j] = fmaxf(rm[j], __shfl_xor(rm[j], mask));

        float Mold[4], Mnew[4];
#pragma unroll
        for (int j = 0; j < 4; ++j) {
            Mold[j] = sM[sr * 4 + j];
            Mnew[j] = fmaxf(Mold[j], rm[j]);
        }
        float p[4][4], ps[4];
#pragma unroll
        for (int j = 0; j < 4; ++j) {
            ps[j] = 0.f;
#pragma unroll
            for (int i = 0; i < 4; ++i) {
                p[j][i] = __expf(s[j][i] - Mnew[j]);
                ps[j] += p[j][i];
            }
        }
#pragma unroll
        for (int mask = 1; mask < 16; mask <<= 1)
#pragma unroll
            for (int j = 0; j < 4; ++j)
                ps[j] += __shfl_xor(ps[j], mask);

        if (sc == 0) {
#pragma unroll
            for (int j = 0; j < 4; ++j) {
                const int n = sr * 4 + j;
                const float f = __expf(Mold[j] - Mnew[j]);
                sF[n] = f;
                sL[n] = sL[n] * f + ps[j];
                sM[n] = Mnew[j];
            }
        }

        // apply edge and write P^T to LDS
#pragma unroll
        for (int j = 0; j < 4; ++j) {
            const int n = n0 + sr * 4 + j;
            const float4 e = *(const float4*)&edge[((size_t)b * N_ + n) * N_ + m0 + sc * 4];
            sPT[sc * 4 + 0][sr * 4 + j] = p[j][0] * e.x;
            sPT[sc * 4 + 1][sr * 4 + j] = p[j][1] * e.y;
            sPT[sc * 4 + 2][sr * 4 + j] = p[j][2] * e.z;
            sPT[sc * 4 + 3][sr * 4 + j] = p[j][3] * e.w;
        }
        __syncthreads();

        // rescale acc and accumulate PV: thread handles d = sr*4+i, n = sc*4+j
        float f[4];
#pragma unroll
        for (int j = 0; j < 4; ++j) f[j] = sF[sc * 4 + j];
#pragma unroll
        for (int i = 0; i < 4; ++i)
#pragma unroll
            for (int j = 0; j < 4; ++j) acc[i][j] *= f[j];
        for (int m = 0; m < 64; ++m) {
            const float4 vv = *(const float4*)&sVT[m][sr * 4];
            const float4 pv = *(const float4*)&sPT[m][sc * 4];
            const float va[4] = {vv.x, vv.y, vv.z, vv.w};
            const float pa[4] = {pv.x, pv.y, pv.z, pv.w};
#pragma unroll
            for (int i = 0; i < 4; ++i)
#pragma unroll
                for (int j = 0; j < 4; ++j)
                    acc[i][j] = fmaf(va[i], pa[j], acc[i][j]);
        }
    }

    // write msg: msg[b][d*H+h][n] = acc / L
    float invL[4];
#pragma unroll
    for (int j = 0; j < 4; ++j) invL[j] = 1.0f / sL[sc * 4 + j];
#pragma unroll
    for (int i = 0; i < 4; ++i) {
        const int d = sr * 4 + i;
        float4 r;
        r.x = acc[i][0] * invL[0];
        r.y = acc[i][1] * invL[1];
        r.z = acc[i][2] * invL[2];
        r.w = acc[i][3] * invL[3];
        *(float4*)&msg[((size_t)b * D_ + d * H_ + h) * N_ + n0 + sc * 4] = r;
    }
}

// ---------------------------------------------------------------------------
extern "C" void kernel_launch(void* const* d_in, const int* in_sizes, int n_in,
                              void* d_out, int out_size, void* d_ws, size_t ws_size,
                              hipStream_t stream) {
    const float* x      = (const float*)d_in[0];
    const float* source = (const float*)d_in[1];
    const float* edge   = (const float*)d_in[2];
    const float* Wq = (const float*)d_in[3];
    const float* bq = (const float*)d_in[4];
    const float* Wk = (const float*)d_in[5];
    const float* bk = (const float*)d_in[6];
    const float* Wv = (const float*)d_in[7];
    const float* bv = (const float*)d_in[8];
    const float* Wm = (const float*)d_in[9];
    const float* bm = (const float*)d_in[10];
    const float* W1 = (const float*)d_in[11];
    const float* b1 = (const float*)d_in[12];
    const float* W2 = (const float*)d_in[13];
    const float* b2 = (const float*)d_in[14];
    float* out = (float*)d_out;

    const size_t BDN = (size_t)B_ * D_ * N_;  // 2,097,152
    float* Qw  = (float*)d_ws;
    float* Kw  = Qw + BDN;
    float* Vw  = Kw + BDN;
    float* MSG = Vw + BDN;
    float* MES = MSG + BDN;
    float* H1  = MES + BDN;  // B * 2D * N = 4,194,304 floats

    const dim3 blk(256);
    const dim3 gD(N_ / 64, D_ / 64, B_);       // (32, 4, 4)
    const dim3 g2D(N_ / 64, 2 * D_ / 64, B_);  // (32, 8, 4)

    // Q/K/V projections
    conv1x1_kernel<0><<<gD, blk, 0, stream>>>(x, D_, nullptr, 0, Wq, bq, Qw, D_, D_);
    conv1x1_kernel<0><<<gD, blk, 0, stream>>>(source, D_, nullptr, 0, Wk, bk, Kw, D_, D_);
    conv1x1_kernel<0><<<gD, blk, 0, stream>>>(source, D_, nullptr, 0, Wv, bv, Vw, D_, D_);

    // fused attention -> msg
    attn_kernel<<<dim3(N_ / 64, H_, B_), blk, 0, stream>>>(Qw, Kw, Vw, edge, MSG);

    // merge heads
    conv1x1_kernel<0><<<gD, blk, 0, stream>>>(MSG, D_, nullptr, 0, Wm, bm, MES, D_, D_);
    // MLP: h1 = relu(W1 @ [x; message] + b1)
    conv1x1_kernel<1><<<g2D, blk, 0, stream>>>(x, D_, MES, D_, W1, b1, H1, 2 * D_, 2 * D_);
    // out = W2 @ h1 + b2
    conv1x1_kernel<0><<<gD, blk, 0, stream>>>(H1, 2 * D_, nullptr, 0, W2, b2, out, D_, 2 * D_);
}

// Round 2
// 341.708 us; speedup vs baseline: 1.3537x; 1.3537x over previous
//
#include <hip/hip_runtime.h>
#include <math.h>

#define B_ 4
#define D_ 256
#define N_ 2048
#define H_ 4
#define HD_ 64

typedef __attribute__((ext_vector_type(8))) __bf16 bf16x8;
typedef __attribute__((ext_vector_type(4))) __bf16 bf16x4;
typedef __attribute__((ext_vector_type(4))) float f32x4;

// ---------------------------------------------------------------------------
// conv1x1 GEMM (f32, unchanged from round 1)
// ---------------------------------------------------------------------------
template <int RELU>
__global__ __launch_bounds__(256) void conv1x1_kernel(
    const float* __restrict__ in1, int C1,
    const float* __restrict__ in2, int C2,
    const float* __restrict__ W, const float* __restrict__ bias,
    float* __restrict__ out, int Cout, int K)
{
    const int n0 = blockIdx.x * 64;
    const int o0 = blockIdx.y * 64;
    const int b  = blockIdx.z;
    const int t  = threadIdx.x;
    const int tr = t >> 4;
    const int tc = t & 15;

    __shared__ float sW[16][68];
    __shared__ float sX[16][68];

    float acc[4][4];
#pragma unroll
    for (int i = 0; i < 4; ++i)
#pragma unroll
        for (int j = 0; j < 4; ++j) acc[i][j] = 0.f;

    const int xrow = t >> 4;
    const int xcol = (t & 15) * 4;
    const int wo   = t & 63;
    const int wk   = (t >> 6) * 4;

    for (int k0 = 0; k0 < K; k0 += 16) {
        __syncthreads();
        {
            const int ch = k0 + xrow;
            const float* src;
            if (ch < C1) src = in1 + ((size_t)b * C1 + ch) * N_ + n0 + xcol;
            else         src = in2 + ((size_t)b * C2 + (ch - C1)) * N_ + n0 + xcol;
            const float4 v = *(const float4*)src;
            *(float4*)&sX[xrow][xcol] = v;
        }
        {
            const float4 w = *(const float4*)&W[(size_t)(o0 + wo) * K + k0 + wk];
            sW[wk + 0][wo] = w.x;
            sW[wk + 1][wo] = w.y;
            sW[wk + 2][wo] = w.z;
            sW[wk + 3][wo] = w.w;
        }
        __syncthreads();
#pragma unroll
        for (int k = 0; k < 16; ++k) {
            const float4 wv = *(const float4*)&sW[k][tr * 4];
            const float4 xv = *(const float4*)&sX[k][tc * 4];
            const float wa[4] = {wv.x, wv.y, wv.z, wv.w};
            const float xa[4] = {xv.x, xv.y, xv.z, xv.w};
#pragma unroll
            for (int i = 0; i < 4; ++i)
#pragma unroll
                for (int j = 0; j < 4; ++j)
                    acc[i][j] = fmaf(wa[i], xa[j], acc[i][j]);
        }
    }

#pragma unroll
    for (int i = 0; i < 4; ++i) {
        const int o = o0 + tr * 4 + i;
        const float bs = bias[o];
        float4 r;
        r.x = acc[i][0] + bs;
        r.y = acc[i][1] + bs;
        r.z = acc[i][2] + bs;
        r.w = acc[i][3] + bs;
        if (RELU) {
            r.x = fmaxf(r.x, 0.f); r.y = fmaxf(r.y, 0.f);
            r.z = fmaxf(r.z, 0.f); r.w = fmaxf(r.w, 0.f);
        }
        *(float4*)&out[((size_t)b * Cout + o) * N_ + n0 + tc * 4] = r;
    }
}

// ---------------------------------------------------------------------------
// MFMA bf16 fused attention per (b, h).
// Block: 256 threads = 4 waves, handles 64 q-rows (n0..n0+63).
// Wave w owns n in [16w,16w+16) for QK^T/softmax, and d in [16w,16w+16)
// for the PV accumulation (rescale factors broadcast via sF[]).
// K mapping for A/B fragments (identical on both sides — permutation-safe):
//   elem e in 0..7 -> k = 32*kc + 4*(lane>>4) + (e&3) + ((e&4)<<2)
// D mapping (HW-verified): row = 4*(lane>>4)+reg, col = lane&15.
// ---------------------------------------------------------------------------
__global__ __launch_bounds__(256) void attn_kernel(
    const float* __restrict__ Qg, const float* __restrict__ Kg,
    const float* __restrict__ Vg, const float* __restrict__ edge,
    float* __restrict__ msg)
{
    const int n0 = blockIdx.x * 64;
    const int h  = blockIdx.y;
    const int b  = blockIdx.z;
    const int t  = threadIdx.x;
    const int w  = t >> 6;         // wave 0..3
    const int g  = (t >> 4) & 3;   // 16-lane group in wave
    const int c16 = t & 15;        // lane within group

    __shared__ __bf16 sKT[64][72];  // K^T tile: [m][d]
    __shared__ __bf16 sV [64][72];  // V tile:   [d][m]
    __shared__ __bf16 sP [64][72];  // P tile:   [n][m]
    __shared__ float  sF[64];       // per-row rescale factor
    __shared__ float  sLf[64];      // per-row final denominator

    // ---- Q fragments: loaded once, straight from global into registers ----
    bf16x8 qf[2];
#pragma unroll
    for (int kc = 0; kc < 2; ++kc) {
#pragma unroll
        for (int e = 0; e < 8; ++e) {
            const int d = 32 * kc + 4 * g + (e & 3) + ((e & 4) << 2);
            const float qv = Qg[((size_t)b * D_ + d * H_ + h) * N_ + n0 + 16 * w + c16];
            qf[kc][e] = (__bf16)qv;
        }
    }

    f32x4 acc[4];   // PV accumulator: rows d=16w+4g+r, cols n=16*nsub+c16
#pragma unroll
    for (int i = 0; i < 4; ++i) acc[i] = (f32x4){0.f, 0.f, 0.f, 0.f};

    float Mr[4], Lr[4];
#pragma unroll
    for (int r = 0; r < 4; ++r) { Mr[r] = -3.0e38f; Lr[r] = 0.f; }

    const int lrow = t >> 2;         // 0..63: channel-dim row for K/V load
    const int lmc  = (t & 3) * 16;   // m-chunk base

    for (int mt = 0; mt < N_ / 64; ++mt) {
        const int m0 = mt * 64;
        __syncthreads();

        // ---- Phase A: stage K (transposed) and V (straight) as bf16 ----
        {
            const size_t gro = ((size_t)b * D_ + lrow * H_ + h) * N_ + m0 + lmc;
#pragma unroll
            for (int j = 0; j < 4; ++j) {
                const float4 kv = *(const float4*)&Kg[gro + 4 * j];
                sKT[lmc + 4 * j + 0][lrow] = (__bf16)kv.x;
                sKT[lmc + 4 * j + 1][lrow] = (__bf16)kv.y;
                sKT[lmc + 4 * j + 2][lrow] = (__bf16)kv.z;
                sKT[lmc + 4 * j + 3][lrow] = (__bf16)kv.w;
                const float4 vv = *(const float4*)&Vg[gro + 4 * j];
                bf16x4 pv;
                pv[0] = (__bf16)vv.x; pv[1] = (__bf16)vv.y;
                pv[2] = (__bf16)vv.z; pv[3] = (__bf16)vv.w;
                *(bf16x4*)&sV[lrow][lmc + 4 * j] = pv;
            }
        }
        __syncthreads();

        // ---- Phase B: S = (Q^T K)/8, online softmax, P*edge -> sP ----
        f32x4 sfrag[4];
#pragma unroll
        for (int msub = 0; msub < 4; ++msub) {
            f32x4 s = (f32x4){0.f, 0.f, 0.f, 0.f};
#pragma unroll
            for (int kc = 0; kc < 2; ++kc) {
                const bf16x4 b0 = *(const bf16x4*)&sKT[16 * msub + c16][32 * kc + 4 * g];
                const bf16x4 b1 = *(const bf16x4*)&sKT[16 * msub + c16][32 * kc + 16 + 4 * g];
                bf16x8 bf;
#pragma unroll
                for (int i = 0; i < 4; ++i) { bf[i] = b0[i]; bf[i + 4] = b1[i]; }
                s = __builtin_amdgcn_mfma_f32_16x16x32_bf16(qf[kc], bf, s, 0, 0, 0);
            }
#pragma unroll
            for (int r = 0; r < 4; ++r) s[r] *= 0.125f;
            sfrag[msub] = s;
        }

        // row max (rows n = 16w+4g+r live across the 16 lanes of group g)
        float rm[4];
#pragma unroll
        for (int r = 0; r < 4; ++r)
            rm[r] = fmaxf(fmaxf(sfrag[0][r], sfrag[1][r]),
                          fmaxf(sfrag[2][r], sfrag[3][r]));
#pragma unroll
        for (int mask = 1; mask < 16; mask <<= 1)
#pragma unroll
            for (int r = 0; r < 4; ++r)
                rm[r] = fmaxf(rm[r], __shfl_xor(rm[r], mask));

        float Mnew[4], fr[4], p[4][4], ps[4];
#pragma unroll
        for (int r = 0; r < 4; ++r) {
            Mnew[r] = fmaxf(Mr[r], rm[r]);
            fr[r]   = __expf(Mr[r] - Mnew[r]);
            ps[r]   = 0.f;
#pragma unroll
            for (int msub = 0; msub < 4; ++msub) {
                p[msub][r] = __expf(sfrag[msub][r] - Mnew[r]);
                ps[r] += p[msub][r];
            }
        }
#pragma unroll
        for (int mask = 1; mask < 16; mask <<= 1)
#pragma unroll
            for (int r = 0; r < 4; ++r)
                ps[r] += __shfl_xor(ps[r], mask);
#pragma unroll
        for (int r = 0; r < 4; ++r) {
            Lr[r] = Lr[r] * fr[r] + ps[r];
            Mr[r] = Mnew[r];
        }
        if (c16 == 0) {
#pragma unroll
            for (int r = 0; r < 4; ++r) sF[16 * w + 4 * g + r] = fr[r];
        }

        // apply edge, store P (bf16) as [n][m]
#pragma unroll
        for (int r = 0; r < 4; ++r) {
            const int nloc = 16 * w + 4 * g + r;
            const size_t erow = ((size_t)b * N_ + n0 + nloc) * N_ + m0;
#pragma unroll
            for (int msub = 0; msub < 4; ++msub) {
                const float e = edge[erow + 16 * msub + c16];
                sP[nloc][16 * msub + c16] = (__bf16)(p[msub][r] * e);
            }
        }
        __syncthreads();

        // ---- Phase C: rescale acc, accumulate O += V * P^T ----
#pragma unroll
        for (int nsub = 0; nsub < 4; ++nsub) {
            const float f = sF[16 * nsub + c16];
#pragma unroll
            for (int r = 0; r < 4; ++r) acc[nsub][r] *= f;
        }
#pragma unroll
        for (int kc = 0; kc < 2; ++kc) {
            const bf16x4 a0 = *(const bf16x4*)&sV[16 * w + c16][32 * kc + 4 * g];
            const bf16x4 a1 = *(const bf16x4*)&sV[16 * w + c16][32 * kc + 16 + 4 * g];
            bf16x8 af;
#pragma unroll
            for (int i = 0; i < 4; ++i) { af[i] = a0[i]; af[i + 4] = a1[i]; }
#pragma unroll
            for (int nsub = 0; nsub < 4; ++nsub) {
                const bf16x4 b0 = *(const bf16x4*)&sP[16 * nsub + c16][32 * kc + 4 * g];
                const bf16x4 b1 = *(const bf16x4*)&sP[16 * nsub + c16][32 * kc + 16 + 4 * g];
                bf16x8 bf;
#pragma unroll
                for (int i = 0; i < 4; ++i) { bf[i] = b0[i]; bf[i + 4] = b1[i]; }
                acc[nsub] = __builtin_amdgcn_mfma_f32_16x16x32_bf16(af, bf, acc[nsub], 0, 0, 0);
            }
        }
    }

    // ---- finalize: divide by denominator, write msg ----
    if (c16 == 0) {
#pragma unroll
        for (int r = 0; r < 4; ++r) sLf[16 * w + 4 * g + r] = Lr[r];
    }
    __syncthreads();
#pragma unroll
    for (int nsub = 0; nsub < 4; ++nsub) {
        const float invL = 1.0f / sLf[16 * nsub + c16];
#pragma unroll
        for (int r = 0; r < 4; ++r) {
            const int d = 16 * w + 4 * g + r;
            msg[((size_t)b * D_ + d * H_ + h) * N_ + n0 + 16 * nsub + c16] =
                acc[nsub][r] * invL;
        }
    }
}

// ---------------------------------------------------------------------------
extern "C" void kernel_launch(void* const* d_in, const int* in_sizes, int n_in,
                              void* d_out, int out_size, void* d_ws, size_t ws_size,
                              hipStream_t stream) {
    const float* x      = (const float*)d_in[0];
    const float* source = (const float*)d_in[1];
    const float* edge   = (const float*)d_in[2];
    const float* Wq = (const float*)d_in[3];
    const float* bq = (const float*)d_in[4];
    const float* Wk = (const float*)d_in[5];
    const float* bk = (const float*)d_in[6];
    const float* Wv = (const float*)d_in[7];
    const float* bv = (const float*)d_in[8];
    const float* Wm = (const float*)d_in[9];
    const float* bm = (const float*)d_in[10];
    const float* W1 = (const float*)d_in[11];
    const float* b1 = (const float*)d_in[12];
    const float* W2 = (const float*)d_in[13];
    const float* b2 = (const float*)d_in[14];
    float* out = (float*)d_out;

    const size_t BDN = (size_t)B_ * D_ * N_;
    float* Qw  = (float*)d_ws;
    float* Kw  = Qw + BDN;
    float* Vw  = Kw + BDN;
    float* MSG = Vw + BDN;
    float* MES = MSG + BDN;
    float* H1  = MES + BDN;

    const dim3 blk(256);
    const dim3 gD(N_ / 64, D_ / 64, B_);
    const dim3 g2D(N_ / 64, 2 * D_ / 64, B_);

    conv1x1_kernel<0><<<gD, blk, 0, stream>>>(x, D_, nullptr, 0, Wq, bq, Qw, D_, D_);
    conv1x1_kernel<0><<<gD, blk, 0, stream>>>(source, D_, nullptr, 0, Wk, bk, Kw, D_, D_);
    conv1x1_kernel<0><<<gD, blk, 0, stream>>>(source, D_, nullptr, 0, Wv, bv, Vw, D_, D_);

    attn_kernel<<<dim3(N_ / 64, H_, B_), blk, 0, stream>>>(Qw, Kw, Vw, edge, MSG);

    conv1x1_kernel<0><<<gD, blk, 0, stream>>>(MSG, D_, nullptr, 0, Wm, bm, MES, D_, D_);
    conv1x1_kernel<1><<<g2D, blk, 0, stream>>>(x, D_, MES, D_, W1, b1, H1, 2 * D_, 2 * D_);
    conv1x1_kernel<0><<<gD, blk, 0, stream>>>(H1, 2 * D_, nullptr, 0, W2, b2, out, D_, 2 * D_);
}

// Round 3
// 296.134 us; speedup vs baseline: 1.5620x; 1.1539x over previous
//
#include <hip/hip_runtime.h>
#include <math.h>

#define B_ 4
#define D_ 256
#define N_ 2048
#define H_ 4

typedef __attribute__((ext_vector_type(8))) __bf16 bf16x8;
typedef __attribute__((ext_vector_type(4))) float f32x4;

// ---------------------------------------------------------------------------
// conv1x1 GEMM (f32, unchanged)
// ---------------------------------------------------------------------------
template <int RELU>
__global__ __launch_bounds__(256) void conv1x1_kernel(
    const float* __restrict__ in1, int C1,
    const float* __restrict__ in2, int C2,
    const float* __restrict__ W, const float* __restrict__ bias,
    float* __restrict__ out, int Cout, int K)
{
    const int n0 = blockIdx.x * 64;
    const int o0 = blockIdx.y * 64;
    const int b  = blockIdx.z;
    const int t  = threadIdx.x;
    const int tr = t >> 4;
    const int tc = t & 15;

    __shared__ float sW[16][68];
    __shared__ float sX[16][68];

    float acc[4][4];
#pragma unroll
    for (int i = 0; i < 4; ++i)
#pragma unroll
        for (int j = 0; j < 4; ++j) acc[i][j] = 0.f;

    const int xrow = t >> 4;
    const int xcol = (t & 15) * 4;
    const int wo   = t & 63;
    const int wk   = (t >> 6) * 4;

    for (int k0 = 0; k0 < K; k0 += 16) {
        __syncthreads();
        {
            const int ch = k0 + xrow;
            const float* src;
            if (ch < C1) src = in1 + ((size_t)b * C1 + ch) * N_ + n0 + xcol;
            else         src = in2 + ((size_t)b * C2 + (ch - C1)) * N_ + n0 + xcol;
            const float4 v = *(const float4*)src;
            *(float4*)&sX[xrow][xcol] = v;
        }
        {
            const float4 w = *(const float4*)&W[(size_t)(o0 + wo) * K + k0 + wk];
            sW[wk + 0][wo] = w.x;
            sW[wk + 1][wo] = w.y;
            sW[wk + 2][wo] = w.z;
            sW[wk + 3][wo] = w.w;
        }
        __syncthreads();
#pragma unroll
        for (int k = 0; k < 16; ++k) {
            const float4 wv = *(const float4*)&sW[k][tr * 4];
            const float4 xv = *(const float4*)&sX[k][tc * 4];
            const float wa[4] = {wv.x, wv.y, wv.z, wv.w};
            const float xa[4] = {xv.x, xv.y, xv.z, xv.w};
#pragma unroll
            for (int i = 0; i < 4; ++i)
#pragma unroll
                for (int j = 0; j < 4; ++j)
                    acc[i][j] = fmaf(wa[i], xa[j], acc[i][j]);
        }
    }

#pragma unroll
    for (int i = 0; i < 4; ++i) {
        const int o = o0 + tr * 4 + i;
        const float bs = bias[o];
        float4 r;
        r.x = acc[i][0] + bs;
        r.y = acc[i][1] + bs;
        r.z = acc[i][2] + bs;
        r.w = acc[i][3] + bs;
        if (RELU) {
            r.x = fmaxf(r.x, 0.f); r.y = fmaxf(r.y, 0.f);
            r.z = fmaxf(r.z, 0.f); r.w = fmaxf(r.w, 0.f);
        }
        *(float4*)&out[((size_t)b * Cout + o) * N_ + n0 + tc * 4] = r;
    }
}

// ---------------------------------------------------------------------------
// MFMA bf16 fused attention, pipelined + defer-max.
// Block = 4 waves, one (b,h), 64 q-rows. m-tiles of 64, software-pipelined:
//   phase C: issue loads(t+1); QK^T from sKT; defer-max softmax; P*edge->sP
//   barrier D
//   phase E: acc-rescale; PV from sV[cur]+sP; LDS-write staged regs(t+1)
//   barrier F
// k-fragment mapping (both operands, permutation-invariant): elem e of
// (kc,g) chunk <-> k = 32*kc + 8*g + e  => every fragment is ONE b128 read.
// Scale 1/8 folded into Q. L accumulated per-lane, reduced once at the end.
// ---------------------------------------------------------------------------
__global__ __launch_bounds__(256) void attn_kernel(
    const float* __restrict__ Qg, const float* __restrict__ Kg,
    const float* __restrict__ Vg, const float* __restrict__ edge,
    float* __restrict__ msg)
{
    const int n0 = blockIdx.x * 64;
    const int h  = blockIdx.y;
    const int b  = blockIdx.z;
    const int t  = threadIdx.x;
    const int w  = t >> 6;
    const int g  = (t >> 4) & 3;
    const int c16 = t & 15;

    __shared__ __bf16 sKT[64][72];      // K^T [m][d], single buffer
    __shared__ __bf16 sV[2][64][72];    // V [d][m], double buffer
    __shared__ __bf16 sP[64][72];       // P [n][m]
    __shared__ float  sE[64][68];       // edge tile [n][m]
    __shared__ float  sF[64];           // per-row rescale factor
    __shared__ float  sLf[64];          // final denominators

    // ---- Q fragments (pre-scaled by 1/sqrt(64)) ----
    bf16x8 qf[2];
#pragma unroll
    for (int kc = 0; kc < 2; ++kc)
#pragma unroll
        for (int e = 0; e < 8; ++e) {
            const int d = 32 * kc + 8 * g + e;
            qf[kc][e] = (__bf16)(0.125f *
                Qg[((size_t)b * D_ + d * H_ + h) * N_ + n0 + 16 * w + c16]);
        }

    f32x4 acc[4];
#pragma unroll
    for (int i = 0; i < 4; ++i) acc[i] = (f32x4){0.f, 0.f, 0.f, 0.f};
    float M[4], Lr[4];
#pragma unroll
    for (int r = 0; r < 4; ++r) { M[r] = -3.0e38f; Lr[r] = 0.f; }

    // staging assignment: lane d_ld = t&63 loads row d, m-chunk = wave*16
    const int d_ld = t & 63;
    const int wv   = t >> 6;
    const size_t kvbase = ((size_t)b * D_ + d_ld * H_ + h) * N_ + wv * 16;
    const size_t ebase  = ((size_t)b * N_ + n0 + (t >> 2)) * N_ + (t & 3) * 16;

    float4 kreg[4], vreg[4], ereg[4];

    auto LOAD = [&](int m0) {
#pragma unroll
        for (int j = 0; j < 4; ++j) {
            kreg[j] = *(const float4*)&Kg[kvbase + m0 + 4 * j];
            vreg[j] = *(const float4*)&Vg[kvbase + m0 + 4 * j];
            ereg[j] = *(const float4*)&edge[ebase + m0 + 4 * j];
        }
    };
    auto WRITE = [&](int buf) {
        // K transpose: (d=d_ld, m=16wv+4j+i) -> sKT[m][d]; wave-contiguous 2B
#pragma unroll
        for (int j = 0; j < 4; ++j) {
            const float kf[4] = {kreg[j].x, kreg[j].y, kreg[j].z, kreg[j].w};
#pragma unroll
            for (int i = 0; i < 4; ++i)
                sKT[wv * 16 + 4 * j + i][d_ld] = (__bf16)kf[i];
        }
        // V straight: two bf16x8 stores
        bf16x8 v0, v1;
        v0[0] = (__bf16)vreg[0].x; v0[1] = (__bf16)vreg[0].y;
        v0[2] = (__bf16)vreg[0].z; v0[3] = (__bf16)vreg[0].w;
        v0[4] = (__bf16)vreg[1].x; v0[5] = (__bf16)vreg[1].y;
        v0[6] = (__bf16)vreg[1].z; v0[7] = (__bf16)vreg[1].w;
        v1[0] = (__bf16)vreg[2].x; v1[1] = (__bf16)vreg[2].y;
        v1[2] = (__bf16)vreg[2].z; v1[3] = (__bf16)vreg[2].w;
        v1[4] = (__bf16)vreg[3].x; v1[5] = (__bf16)vreg[3].y;
        v1[6] = (__bf16)vreg[3].z; v1[7] = (__bf16)vreg[3].w;
        *(bf16x8*)&sV[buf][d_ld][wv * 16]     = v0;
        *(bf16x8*)&sV[buf][d_ld][wv * 16 + 8] = v1;
        // edge tile
#pragma unroll
        for (int j = 0; j < 4; ++j)
            *(float4*)&sE[t >> 2][(t & 3) * 16 + 4 * j] = ereg[j];
    };

    // ---- prologue: stage tile 0 ----
    LOAD(0);
    WRITE(0);
    __syncthreads();

    for (int mt = 0; mt < 32; ++mt) {
        const int cur = mt & 1;
        const int m0n = (mt < 31 ? mt + 1 : mt) * 64;

        // prefetch tile t+1 into registers (drained at barrier D)
        LOAD(m0n);

        // ---- phase C: QK^T ----
        f32x4 sfrag[4];
#pragma unroll
        for (int msub = 0; msub < 4; ++msub) {
            f32x4 s = (f32x4){0.f, 0.f, 0.f, 0.f};
#pragma unroll
            for (int kc = 0; kc < 2; ++kc) {
                const bf16x8 bfr = *(const bf16x8*)&sKT[16 * msub + c16][32 * kc + 8 * g];
                s = __builtin_amdgcn_mfma_f32_16x16x32_bf16(qf[kc], bfr, s, 0, 0, 0);
            }
            sfrag[msub] = s;
        }

        // defer-max online softmax (no cross-lane in common path)
        float rm[4];
#pragma unroll
        for (int r = 0; r < 4; ++r)
            rm[r] = fmaxf(fmaxf(sfrag[0][r], sfrag[1][r]),
                          fmaxf(sfrag[2][r], sfrag[3][r]));
        int need = 0;
#pragma unroll
        for (int r = 0; r < 4; ++r) need |= (rm[r] > M[r] + 8.0f) ? 1 : 0;

        float fr[4];
        if (__any(need)) {
#pragma unroll
            for (int mask = 1; mask < 16; mask <<= 1)
#pragma unroll
                for (int r = 0; r < 4; ++r)
                    rm[r] = fmaxf(rm[r], __shfl_xor(rm[r], mask));
#pragma unroll
            for (int r = 0; r < 4; ++r) {
                const float Mn = fmaxf(M[r], rm[r]);
                fr[r] = __expf(M[r] - Mn);
                M[r]  = Mn;
                Lr[r] *= fr[r];
            }
        } else {
#pragma unroll
            for (int r = 0; r < 4; ++r) fr[r] = 1.0f;
        }
        if (c16 == 0) {
#pragma unroll
            for (int r = 0; r < 4; ++r) sF[16 * w + 4 * g + r] = fr[r];
        }

        // p = exp(s - M); L += p; sP = bf16(p * edge)
#pragma unroll
        for (int msub = 0; msub < 4; ++msub) {
#pragma unroll
            for (int r = 0; r < 4; ++r) {
                const int nloc = 16 * w + 4 * g + r;
                const float p = __expf(sfrag[msub][r] - M[r]);
                Lr[r] += p;
                const float e = sE[nloc][16 * msub + c16];
                sP[nloc][16 * msub + c16] = (__bf16)(p * e);
            }
        }

        __syncthreads();  // D: sP/sF ready; prefetch regs arrived

        // ---- phase E: rescale + PV ----
#pragma unroll
        for (int nsub = 0; nsub < 4; ++nsub) {
            const float f = sF[16 * nsub + c16];
            acc[nsub] *= f;
        }
#pragma unroll
        for (int kc = 0; kc < 2; ++kc) {
            const bf16x8 af = *(const bf16x8*)&sV[cur][16 * w + c16][32 * kc + 8 * g];
#pragma unroll
            for (int nsub = 0; nsub < 4; ++nsub) {
                const bf16x8 bfr = *(const bf16x8*)&sP[16 * nsub + c16][32 * kc + 8 * g];
                acc[nsub] = __builtin_amdgcn_mfma_f32_16x16x32_bf16(af, bfr, acc[nsub], 0, 0, 0);
            }
        }

        // stage tile t+1 into LDS (sKT, sE single-buffer safe post-D)
        WRITE(cur ^ 1);

        __syncthreads();  // F: staging visible for next tile
    }

    // ---- final: reduce per-lane L partials, divide, store ----
#pragma unroll
    for (int mask = 1; mask < 16; mask <<= 1)
#pragma unroll
        for (int r = 0; r < 4; ++r) Lr[r] += __shfl_xor(Lr[r], mask);
    if (c16 == 0) {
#pragma unroll
        for (int r = 0; r < 4; ++r) sLf[16 * w + 4 * g + r] = Lr[r];
    }
    __syncthreads();
#pragma unroll
    for (int nsub = 0; nsub < 4; ++nsub) {
        const float invL = 1.0f / sLf[16 * nsub + c16];
#pragma unroll
        for (int r = 0; r < 4; ++r) {
            const int d = 16 * w + 4 * g + r;
            msg[((size_t)b * D_ + d * H_ + h) * N_ + n0 + 16 * nsub + c16] =
                acc[nsub][r] * invL;
        }
    }
}

// ---------------------------------------------------------------------------
extern "C" void kernel_launch(void* const* d_in, const int* in_sizes, int n_in,
                              void* d_out, int out_size, void* d_ws, size_t ws_size,
                              hipStream_t stream) {
    const float* x      = (const float*)d_in[0];
    const float* source = (const float*)d_in[1];
    const float* edge   = (const float*)d_in[2];
    const float* Wq = (const float*)d_in[3];
    const float* bq = (const float*)d_in[4];
    const float* Wk = (const float*)d_in[5];
    const float* bk = (const float*)d_in[6];
    const float* Wv = (const float*)d_in[7];
    const float* bv = (const float*)d_in[8];
    const float* Wm = (const float*)d_in[9];
    const float* bm = (const float*)d_in[10];
    const float* W1 = (const float*)d_in[11];
    const float* b1 = (const float*)d_in[12];
    const float* W2 = (const float*)d_in[13];
    const float* b2 = (const float*)d_in[14];
    float* out = (float*)d_out;

    const size_t BDN = (size_t)B_ * D_ * N_;
    float* Qw  = (float*)d_ws;
    float* Kw  = Qw + BDN;
    float* Vw  = Kw + BDN;
    float* MSG = Vw + BDN;
    float* MES = MSG + BDN;
    float* H1  = MES + BDN;

    const dim3 blk(256);
    const dim3 gD(N_ / 64, D_ / 64, B_);
    const dim3 g2D(N_ / 64, 2 * D_ / 64, B_);

    conv1x1_kernel<0><<<gD, blk, 0, stream>>>(x, D_, nullptr, 0, Wq, bq, Qw, D_, D_);
    conv1x1_kernel<0><<<gD, blk, 0, stream>>>(source, D_, nullptr, 0, Wk, bk, Kw, D_, D_);
    conv1x1_kernel<0><<<gD, blk, 0, stream>>>(source, D_, nullptr, 0, Wv, bv, Vw, D_, D_);

    attn_kernel<<<dim3(N_ / 64, H_, B_), blk, 0, stream>>>(Qw, Kw, Vw, edge, MSG);

    conv1x1_kernel<0><<<gD, blk, 0, stream>>>(MSG, D_, nullptr, 0, Wm, bm, MES, D_, D_);
    conv1x1_kernel<1><<<g2D, blk, 0, stream>>>(x, D_, MES, D_, W1, b1, H1, 2 * D_, 2 * D_);
    conv1x1_kernel<0><<<gD, blk, 0, stream>>>(H1, 2 * D_, nullptr, 0, W2, b2, out, D_, 2 * D_);
}

// Round 4
// 280.272 us; speedup vs baseline: 1.6504x; 1.0566x over previous
//
#include <hip/hip_runtime.h>
#include <math.h>

#define B_ 4
#define D_ 256
#define N_ 2048
#define H_ 4

typedef __attribute__((ext_vector_type(8))) __bf16 bf16x8;
typedef __attribute__((ext_vector_type(4))) __bf16 bf16x4;
typedef __attribute__((ext_vector_type(4))) float f32x4;

// ---------------------------------------------------------------------------
// conv1x1 GEMM (f32, unchanged)
// ---------------------------------------------------------------------------
template <int RELU>
__global__ __launch_bounds__(256) void conv1x1_kernel(
    const float* __restrict__ in1, int C1,
    const float* __restrict__ in2, int C2,
    const float* __restrict__ W, const float* __restrict__ bias,
    float* __restrict__ out, int Cout, int K)
{
    const int n0 = blockIdx.x * 64;
    const int o0 = blockIdx.y * 64;
    const int b  = blockIdx.z;
    const int t  = threadIdx.x;
    const int tr = t >> 4;
    const int tc = t & 15;

    __shared__ float sW[16][68];
    __shared__ float sX[16][68];

    float acc[4][4];
#pragma unroll
    for (int i = 0; i < 4; ++i)
#pragma unroll
        for (int j = 0; j < 4; ++j) acc[i][j] = 0.f;

    const int xrow = t >> 4;
    const int xcol = (t & 15) * 4;
    const int wo   = t & 63;
    const int wk   = (t >> 6) * 4;

    for (int k0 = 0; k0 < K; k0 += 16) {
        __syncthreads();
        {
            const int ch = k0 + xrow;
            const float* src;
            if (ch < C1) src = in1 + ((size_t)b * C1 + ch) * N_ + n0 + xcol;
            else         src = in2 + ((size_t)b * C2 + (ch - C1)) * N_ + n0 + xcol;
            const float4 v = *(const float4*)src;
            *(float4*)&sX[xrow][xcol] = v;
        }
        {
            const float4 w = *(const float4*)&W[(size_t)(o0 + wo) * K + k0 + wk];
            sW[wk + 0][wo] = w.x;
            sW[wk + 1][wo] = w.y;
            sW[wk + 2][wo] = w.z;
            sW[wk + 3][wo] = w.w;
        }
        __syncthreads();
#pragma unroll
        for (int k = 0; k < 16; ++k) {
            const float4 wv = *(const float4*)&sW[k][tr * 4];
            const float4 xv = *(const float4*)&sX[k][tc * 4];
            const float wa[4] = {wv.x, wv.y, wv.z, wv.w};
            const float xa[4] = {xv.x, xv.y, xv.z, xv.w};
#pragma unroll
            for (int i = 0; i < 4; ++i)
#pragma unroll
                for (int j = 0; j < 4; ++j)
                    acc[i][j] = fmaf(wa[i], xa[j], acc[i][j]);
        }
    }

#pragma unroll
    for (int i = 0; i < 4; ++i) {
        const int o = o0 + tr * 4 + i;
        const float bs = bias[o];
        float4 r;
        r.x = acc[i][0] + bs;
        r.y = acc[i][1] + bs;
        r.z = acc[i][2] + bs;
        r.w = acc[i][3] + bs;
        if (RELU) {
            r.x = fmaxf(r.x, 0.f); r.y = fmaxf(r.y, 0.f);
            r.z = fmaxf(r.z, 0.f); r.w = fmaxf(r.w, 0.f);
        }
        *(float4*)&out[((size_t)b * Cout + o) * N_ + n0 + tc * 4] = r;
    }
}

// ---------------------------------------------------------------------------
// MFMA bf16 fused attention, m-split flash style.
// Block = 4 waves, one (b, h, split). 64 q-rows, MT = 32/NSPLIT m-tiles.
// LDS: only sKT (K^T) and sP. V: per-wave direct global->reg (wave w uses
// only d rows 16w..16w+15). Edge: per-lane direct loads of the exact 16
// scalars consumed (64B-coalesced per 16-lane group).
// Outputs partials: OP[pid][64d][64n] bf16, ML[pid][{M,L}][64n] f32.
// ---------------------------------------------------------------------------
template <int NSPLIT>
__global__ __launch_bounds__(256, 4) void attn_kernel(
    const float* __restrict__ Qg, const float* __restrict__ Kg,
    const float* __restrict__ Vg, const float* __restrict__ edge,
    __bf16* __restrict__ OP, float* __restrict__ ML)
{
    const int nt    = blockIdx.x;
    const int n0    = nt * 64;
    const int split = blockIdx.y % NSPLIT;
    const int h     = blockIdx.y / NSPLIT;
    const int b     = blockIdx.z;
    const int t  = threadIdx.x;
    const int w  = t >> 6;
    const int g  = (t >> 4) & 3;
    const int c16 = t & 15;

    const int MT   = 32 / NSPLIT;
    const int m_lo = split * (N_ / NSPLIT);
    const int pid  = ((b * H_ + h) * NSPLIT + split) * 32 + nt;

    __shared__ __bf16 sKT[64][72];  // K^T [m][d]
    __shared__ __bf16 sP [64][72];  // P [n][m]
    __shared__ float  sF[64];       // per-row rescale factors

    // ---- Q fragments (pre-scaled by 1/sqrt(64)); k = 32kc+8g+e ----
    bf16x8 qf[2];
#pragma unroll
    for (int kc = 0; kc < 2; ++kc)
#pragma unroll
        for (int e = 0; e < 8; ++e) {
            const int d = 32 * kc + 8 * g + e;
            qf[kc][e] = (__bf16)(0.125f *
                Qg[((size_t)b * D_ + d * H_ + h) * N_ + n0 + 16 * w + c16]);
        }

    f32x4 acc[4];
#pragma unroll
    for (int i = 0; i < 4; ++i) acc[i] = (f32x4){0.f, 0.f, 0.f, 0.f};
    float M[4], Lr[4];
#pragma unroll
    for (int r = 0; r < 4; ++r) { M[r] = -3.0e38f; Lr[r] = 0.f; }

    // K staging: lane d_ld loads channel-row d_ld, m-chunk = wave*16
    const int d_ld = t & 63;
    const int wv   = t >> 6;
    const size_t kbase = ((size_t)b * D_ + d_ld * H_ + h) * N_ + m_lo + wv * 16;
    // V direct: wave w, lane c16 -> V row d=16w+c16
    const size_t vrow = ((size_t)b * D_ + (16 * w + c16) * H_ + h) * N_ + m_lo;
    // edge direct: rows n0+16w+4g+r, cols m_lo+m0+16*ms+c16
    const size_t ebase = ((size_t)b * N_ + n0 + 16 * w + 4 * g) * N_ + m_lo + c16;

    float4 kreg[4];
    float4 vreg[4];
    float  ereg[4][4];  // [r][msub]

    auto LOADK = [&](int m0) {
#pragma unroll
        for (int j = 0; j < 4; ++j) kreg[j] = *(const float4*)&Kg[kbase + m0 + 4 * j];
    };
    auto LOADV = [&](int m0) {
        vreg[0] = *(const float4*)&Vg[vrow + m0 + 8 * g];
        vreg[1] = *(const float4*)&Vg[vrow + m0 + 8 * g + 4];
        vreg[2] = *(const float4*)&Vg[vrow + m0 + 32 + 8 * g];
        vreg[3] = *(const float4*)&Vg[vrow + m0 + 32 + 8 * g + 4];
    };
    auto LOADE = [&](int m0) {
#pragma unroll
        for (int r = 0; r < 4; ++r)
#pragma unroll
            for (int ms = 0; ms < 4; ++ms)
                ereg[r][ms] = edge[ebase + (size_t)r * N_ + m0 + 16 * ms];
    };
    auto WRITEKT = [&]() {
#pragma unroll
        for (int j = 0; j < 4; ++j) {
            const float kf[4] = {kreg[j].x, kreg[j].y, kreg[j].z, kreg[j].w};
#pragma unroll
            for (int i = 0; i < 4; ++i)
                sKT[wv * 16 + 4 * j + i][d_ld] = (__bf16)kf[i];
        }
    };

    // ---- prologue ----
    LOADK(0);
    LOADV(0);
    LOADE(0);
    WRITEKT();
    __syncthreads();

    for (int mt = 0; mt < MT; ++mt) {
        const int m0n = (mt < MT - 1 ? mt + 1 : mt) * 64;

        LOADK(m0n);
        // consume V(t) into fragments, then prefetch V(t+1)
        bf16x8 af[2];
#pragma unroll
        for (int kc = 0; kc < 2; ++kc)
#pragma unroll
            for (int e = 0; e < 8; ++e) {
                const float* vp = (const float*)&vreg[2 * kc + (e >> 2)];
                af[kc][e] = (__bf16)vp[e & 3];
            }
        LOADV(m0n);

        // ---- phase C: QK^T ----
        f32x4 sfrag[4];
#pragma unroll
        for (int msub = 0; msub < 4; ++msub) {
            f32x4 s = (f32x4){0.f, 0.f, 0.f, 0.f};
#pragma unroll
            for (int kc = 0; kc < 2; ++kc) {
                const bf16x8 bfr = *(const bf16x8*)&sKT[16 * msub + c16][32 * kc + 8 * g];
                s = __builtin_amdgcn_mfma_f32_16x16x32_bf16(qf[kc], bfr, s, 0, 0, 0);
            }
            sfrag[msub] = s;
        }

        // defer-max online softmax
        float rm[4];
#pragma unroll
        for (int r = 0; r < 4; ++r)
            rm[r] = fmaxf(fmaxf(sfrag[0][r], sfrag[1][r]),
                          fmaxf(sfrag[2][r], sfrag[3][r]));
        int need = 0;
#pragma unroll
        for (int r = 0; r < 4; ++r) need |= (rm[r] > M[r] + 8.0f) ? 1 : 0;

        float fr[4];
        if (__any(need)) {
#pragma unroll
            for (int mask = 1; mask < 16; mask <<= 1)
#pragma unroll
                for (int r = 0; r < 4; ++r)
                    rm[r] = fmaxf(rm[r], __shfl_xor(rm[r], mask));
#pragma unroll
            for (int r = 0; r < 4; ++r) {
                const float Mn = fmaxf(M[r], rm[r]);
                fr[r] = __expf(M[r] - Mn);
                M[r]  = Mn;
                Lr[r] *= fr[r];
            }
        } else {
#pragma unroll
            for (int r = 0; r < 4; ++r) fr[r] = 1.0f;
        }
        if (c16 == 0) {
#pragma unroll
            for (int r = 0; r < 4; ++r) sF[16 * w + 4 * g + r] = fr[r];
        }

        // p = exp(s - M); L += p; sP = bf16(p * edge)
#pragma unroll
        for (int msub = 0; msub < 4; ++msub) {
#pragma unroll
            for (int r = 0; r < 4; ++r) {
                const int nloc = 16 * w + 4 * g + r;
                const float p = __expf(sfrag[msub][r] - M[r]);
                Lr[r] += p;
                sP[nloc][16 * msub + c16] = (__bf16)(p * ereg[r][msub]);
            }
        }
        LOADE(m0n);

        __syncthreads();  // D: sP/sF ready

        // ---- phase E: rescale + PV + stage K(t+1) ----
#pragma unroll
        for (int nsub = 0; nsub < 4; ++nsub) {
            const float f = sF[16 * nsub + c16];
            acc[nsub] *= f;
        }
#pragma unroll
        for (int kc = 0; kc < 2; ++kc) {
#pragma unroll
            for (int nsub = 0; nsub < 4; ++nsub) {
                const bf16x8 bfr = *(const bf16x8*)&sP[16 * nsub + c16][32 * kc + 8 * g];
                acc[nsub] = __builtin_amdgcn_mfma_f32_16x16x32_bf16(af[kc], bfr, acc[nsub], 0, 0, 0);
            }
        }
        WRITEKT();

        __syncthreads();  // F: sKT(t+1) visible
    }

    // ---- epilogue: reduce L, write partial state ----
#pragma unroll
    for (int mask = 1; mask < 16; mask <<= 1)
#pragma unroll
        for (int r = 0; r < 4; ++r) Lr[r] += __shfl_xor(Lr[r], mask);
    if (c16 == 0) {
#pragma unroll
        for (int r = 0; r < 4; ++r) {
            const int nloc = 16 * w + 4 * g + r;
            ML[(size_t)pid * 128 + nloc]      = M[r];
            ML[(size_t)pid * 128 + 64 + nloc] = Lr[r];
        }
    }
#pragma unroll
    for (int nsub = 0; nsub < 4; ++nsub)
#pragma unroll
        for (int r = 0; r < 4; ++r) {
            const int dd = 16 * w + 4 * g + r;
            OP[(size_t)pid * 4096 + dd * 64 + 16 * nsub + c16] = (__bf16)acc[nsub][r];
        }
}

// ---------------------------------------------------------------------------
// Combine m-split partials: msg = (sum_s e^{M_s-Mx} * A_s) / (sum_s e^{M_s-Mx} * L_s)
// ---------------------------------------------------------------------------
template <int NSPLIT>
__global__ __launch_bounds__(256) void combine_kernel(
    const __bf16* __restrict__ OP, const float* __restrict__ ML,
    float* __restrict__ msg)
{
    const int nt = blockIdx.x;
    const int h  = blockIdx.y;
    const int b  = blockIdx.z;
    const int t  = threadIdx.x;
    const int d  = t & 63;
    const int seg = t >> 6;
    const int pid0 = ((b * H_ + h) * NSPLIT) * 32 + nt;

    __shared__ float sM[NSPLIT][64], sL[NSPLIT][64];
    if (t < NSPLIT * 64) {
        const int s = t >> 6, n = t & 63;
        sM[s][n] = ML[(size_t)(pid0 + s * 32) * 128 + n];
        sL[s][n] = ML[(size_t)(pid0 + s * 32) * 128 + 64 + n];
    }
    __syncthreads();

#pragma unroll
    for (int q = 0; q < 4; ++q) {
        const int c0 = seg * 16 + q * 4;
        float o[4] = {0.f, 0.f, 0.f, 0.f};
        float wgt[NSPLIT][4];
#pragma unroll
        for (int j = 0; j < 4; ++j) {
            float mx = -3.0e38f;
            for (int s = 0; s < NSPLIT; ++s) mx = fmaxf(mx, sM[s][c0 + j]);
            float den = 0.f;
            for (int s = 0; s < NSPLIT; ++s) {
                wgt[s][j] = __expf(sM[s][c0 + j] - mx);
                den += wgt[s][j] * sL[s][c0 + j];
            }
            const float inv = 1.0f / den;
            for (int s = 0; s < NSPLIT; ++s) wgt[s][j] *= inv;
        }
        for (int s = 0; s < NSPLIT; ++s) {
            const bf16x4 a = *(const bf16x4*)&OP[(size_t)(pid0 + s * 32) * 4096 + d * 64 + c0];
#pragma unroll
            for (int j = 0; j < 4; ++j) o[j] += wgt[s][j] * (float)a[j];
        }
        float4 r = {o[0], o[1], o[2], o[3]};
        *(float4*)&msg[((size_t)b * D_ + d * H_ + h) * N_ + nt * 64 + c0] = r;
    }
}

// ---------------------------------------------------------------------------
extern "C" void kernel_launch(void* const* d_in, const int* in_sizes, int n_in,
                              void* d_out, int out_size, void* d_ws, size_t ws_size,
                              hipStream_t stream) {
    const float* x      = (const float*)d_in[0];
    const float* source = (const float*)d_in[1];
    const float* edge   = (const float*)d_in[2];
    const float* Wq = (const float*)d_in[3];
    const float* bq = (const float*)d_in[4];
    const float* Wk = (const float*)d_in[5];
    const float* bk = (const float*)d_in[6];
    const float* Wv = (const float*)d_in[7];
    const float* bv = (const float*)d_in[8];
    const float* Wm = (const float*)d_in[9];
    const float* bm = (const float*)d_in[10];
    const float* W1 = (const float*)d_in[11];
    const float* b1 = (const float*)d_in[12];
    const float* W2 = (const float*)d_in[13];
    const float* b2 = (const float*)d_in[14];
    float* out = (float*)d_out;

    const size_t BDN = (size_t)B_ * D_ * N_;
    float* Qw  = (float*)d_ws;
    float* Kw  = Qw + BDN;
    float* Vw  = Kw + BDN;
    float* MSG = Vw + BDN;
    float* MES = MSG + BDN;
    float* H1  = MES + BDN;           // 2*BDN floats
    char*  tail = (char*)(H1 + 2 * BDN);
    const size_t baseBytes = (size_t)7 * BDN * 4;

    // partial buffers: OP bf16 [NS*B*H*32][4096], ML f32 [NS*B*H*32][128]
    const size_t pids2 = (size_t)2 * B_ * H_ * 32;
    const size_t need2 = baseBytes + pids2 * 4096 * 2 + pids2 * 128 * 4;
    const bool use2 = (ws_size >= need2);

    const dim3 blk(256);
    const dim3 gD(N_ / 64, D_ / 64, B_);
    const dim3 g2D(N_ / 64, 2 * D_ / 64, B_);

    conv1x1_kernel<0><<<gD, blk, 0, stream>>>(x, D_, nullptr, 0, Wq, bq, Qw, D_, D_);
    conv1x1_kernel<0><<<gD, blk, 0, stream>>>(source, D_, nullptr, 0, Wk, bk, Kw, D_, D_);
    conv1x1_kernel<0><<<gD, blk, 0, stream>>>(source, D_, nullptr, 0, Wv, bv, Vw, D_, D_);

    if (use2) {
        __bf16* OP = (__bf16*)tail;
        float*  ML = (float*)(tail + pids2 * 4096 * 2);
        attn_kernel<2><<<dim3(32, H_ * 2, B_), blk, 0, stream>>>(Qw, Kw, Vw, edge, OP, ML);
        combine_kernel<2><<<dim3(32, H_, B_), blk, 0, stream>>>(OP, ML, MSG);
    } else {
        const size_t pids1 = (size_t)B_ * H_ * 32;
        __bf16* OP = (__bf16*)tail;
        float*  ML = (float*)(tail + pids1 * 4096 * 2);
        attn_kernel<1><<<dim3(32, H_, B_), blk, 0, stream>>>(Qw, Kw, Vw, edge, OP, ML);
        combine_kernel<1><<<dim3(32, H_, B_), blk, 0, stream>>>(OP, ML, MSG);
    }

    conv1x1_kernel<0><<<gD, blk, 0, stream>>>(MSG, D_, nullptr, 0, Wm, bm, MES, D_, D_);
    conv1x1_kernel<1><<<g2D, blk, 0, stream>>>(x, D_, MES, D_, W1, b1, H1, 2 * D_, 2 * D_);
    conv1x1_kernel<0><<<gD, blk, 0, stream>>>(H1, 2 * D_, nullptr, 0, W2, b2, out, D_, 2 * D_);
}

// Round 5
// 198.579 us; speedup vs baseline: 2.3294x; 1.4114x over previous
//
#include <hip/hip_runtime.h>
#include <math.h>

#define B_ 4
#define D_ 256
#define N_ 2048
#define H_ 4

typedef __attribute__((ext_vector_type(8))) __bf16 bf16x8;
typedef __attribute__((ext_vector_type(4))) __bf16 bf16x4;
typedef __attribute__((ext_vector_type(4))) float f32x4;

// ---------------------------------------------------------------------------
// MFMA bf16 conv1x1 tile: out[b, o0:o0+64, n0:n0+64] = act(W @ in + bias)
// in = concat(in1[C1], in2[C2]) channelwise. 4 waves; per-wave C rows
// o = o0+16w+4g+r, cols n = n0+16nsub+c16. k-mapping (both operands):
// elem e of (kc,g) chunk <-> k = ks + 32kc + 8g + e (permutation-invariant).
// X staged transposed in LDS (bf16, 144B stride: 2-way conflicts only);
// W fragments direct global->reg (L2-resident).
// ---------------------------------------------------------------------------
__device__ __forceinline__ void conv_tile(
    const float* __restrict__ in1, int C1,
    const float* __restrict__ in2, int C2,
    const float* __restrict__ Wt, const float* __restrict__ bias,
    float* __restrict__ out, int Cout, int K, int RELU,
    int b, int o0, int n0, __bf16 (*sXT)[72])
{
    const int t = threadIdx.x;
    const int w  = t >> 6;
    const int g  = (t >> 4) & 3;
    const int c16 = t & 15;
    const int d_ld = t & 63;
    const int wv   = t >> 6;

    f32x4 acc[4];
#pragma unroll
    for (int i = 0; i < 4; ++i) acc[i] = (f32x4){0.f, 0.f, 0.f, 0.f};

    float4 xreg[4];
    auto LOADX = [&](int ks) {
        const int ch = ks + d_ld;
        const float* src = (ch < C1)
            ? in1 + ((size_t)b * C1 + ch) * N_ + n0 + wv * 16
            : in2 + ((size_t)b * C2 + (ch - C1)) * N_ + n0 + wv * 16;
#pragma unroll
        for (int j = 0; j < 4; ++j) xreg[j] = *(const float4*)&src[4 * j];
    };
    auto WRITEXT = [&]() {
#pragma unroll
        for (int j = 0; j < 4; ++j) {
            const float xf[4] = {xreg[j].x, xreg[j].y, xreg[j].z, xreg[j].w};
#pragma unroll
            for (int i = 0; i < 4; ++i)
                sXT[wv * 16 + 4 * j + i][d_ld] = (__bf16)xf[i];
        }
    };

    const int ow = o0 + 16 * w + c16;  // W row for A fragment

    LOADX(0);
    WRITEXT();
    __syncthreads();

    for (int ks = 0; ks < K; ks += 64) {
        if (ks + 64 < K) LOADX(ks + 64);

        bf16x8 af[2];
#pragma unroll
        for (int kc = 0; kc < 2; ++kc) {
            const float4 w0 = *(const float4*)&Wt[(size_t)ow * K + ks + 32 * kc + 8 * g];
            const float4 w1 = *(const float4*)&Wt[(size_t)ow * K + ks + 32 * kc + 8 * g + 4];
            af[kc][0] = (__bf16)w0.x; af[kc][1] = (__bf16)w0.y;
            af[kc][2] = (__bf16)w0.z; af[kc][3] = (__bf16)w0.w;
            af[kc][4] = (__bf16)w1.x; af[kc][5] = (__bf16)w1.y;
            af[kc][6] = (__bf16)w1.z; af[kc][7] = (__bf16)w1.w;
        }
#pragma unroll
        for (int kc = 0; kc < 2; ++kc)
#pragma unroll
            for (int nsub = 0; nsub < 4; ++nsub) {
                const bf16x8 bfr = *(const bf16x8*)&sXT[16 * nsub + c16][32 * kc + 8 * g];
                acc[nsub] = __builtin_amdgcn_mfma_f32_16x16x32_bf16(af[kc], bfr, acc[nsub], 0, 0, 0);
            }

        __syncthreads();
        if (ks + 64 < K) WRITEXT();
        __syncthreads();
    }

#pragma unroll
    for (int nsub = 0; nsub < 4; ++nsub)
#pragma unroll
        for (int r = 0; r < 4; ++r) {
            const int o = o0 + 16 * w + 4 * g + r;
            float v = acc[nsub][r] + bias[o];
            if (RELU) v = fmaxf(v, 0.f);
            out[((size_t)b * Cout + o) * N_ + n0 + 16 * nsub + c16] = v;
        }
}

template <int RELU>
__global__ __launch_bounds__(256) void mfma_conv_kernel(
    const float* __restrict__ in1, int C1,
    const float* __restrict__ in2, int C2,
    const float* __restrict__ W, const float* __restrict__ bias,
    float* __restrict__ out, int Cout, int K)
{
    __shared__ __bf16 sXT[64][72];
    conv_tile(in1, C1, in2, C2, W, bias, out, Cout, K, RELU,
              blockIdx.z, blockIdx.y * 64, blockIdx.x * 64, sXT);
}

// Fused Q/K/V projections: blockIdx.y in [0,12): sel = y>>2 picks {q,k,v}.
__global__ __launch_bounds__(256) void qkv_conv_kernel(
    const float* __restrict__ x, const float* __restrict__ source,
    const float* __restrict__ Wq, const float* __restrict__ bq,
    const float* __restrict__ Wk, const float* __restrict__ bk,
    const float* __restrict__ Wv, const float* __restrict__ bv,
    float* __restrict__ Qo, float* __restrict__ Ko, float* __restrict__ Vo)
{
    __shared__ __bf16 sXT[64][72];
    const int sel = blockIdx.y >> 2;
    const int o0  = (blockIdx.y & 3) * 64;
    const float* in = (sel == 0) ? x : source;
    const float* W  = (sel == 0) ? Wq : (sel == 1) ? Wk : Wv;
    const float* bs = (sel == 0) ? bq : (sel == 1) ? bk : bv;
    float* out      = (sel == 0) ? Qo : (sel == 1) ? Ko : Vo;
    conv_tile(in, D_, nullptr, 0, W, bs, out, D_, D_, 0,
              blockIdx.z, o0, blockIdx.x * 64, sXT);
}

// ---------------------------------------------------------------------------
// MFMA bf16 fused attention, m-split flash style (unchanged from round 4).
// ---------------------------------------------------------------------------
template <int NSPLIT>
__global__ __launch_bounds__(256, 4) void attn_kernel(
    const float* __restrict__ Qg, const float* __restrict__ Kg,
    const float* __restrict__ Vg, const float* __restrict__ edge,
    __bf16* __restrict__ OP, float* __restrict__ ML)
{
    const int nt    = blockIdx.x;
    const int n0    = nt * 64;
    const int split = blockIdx.y % NSPLIT;
    const int h     = blockIdx.y / NSPLIT;
    const int b     = blockIdx.z;
    const int t  = threadIdx.x;
    const int w  = t >> 6;
    const int g  = (t >> 4) & 3;
    const int c16 = t & 15;

    const int MT   = 32 / NSPLIT;
    const int m_lo = split * (N_ / NSPLIT);
    const int pid  = ((b * H_ + h) * NSPLIT + split) * 32 + nt;

    __shared__ __bf16 sKT[64][72];
    __shared__ __bf16 sP [64][72];
    __shared__ float  sF[64];

    bf16x8 qf[2];
#pragma unroll
    for (int kc = 0; kc < 2; ++kc)
#pragma unroll
        for (int e = 0; e < 8; ++e) {
            const int d = 32 * kc + 8 * g + e;
            qf[kc][e] = (__bf16)(0.125f *
                Qg[((size_t)b * D_ + d * H_ + h) * N_ + n0 + 16 * w + c16]);
        }

    f32x4 acc[4];
#pragma unroll
    for (int i = 0; i < 4; ++i) acc[i] = (f32x4){0.f, 0.f, 0.f, 0.f};
    float M[4], Lr[4];
#pragma unroll
    for (int r = 0; r < 4; ++r) { M[r] = -3.0e38f; Lr[r] = 0.f; }

    const int d_ld = t & 63;
    const int wv   = t >> 6;
    const size_t kbase = ((size_t)b * D_ + d_ld * H_ + h) * N_ + m_lo + wv * 16;
    const size_t vrow = ((size_t)b * D_ + (16 * w + c16) * H_ + h) * N_ + m_lo;
    const size_t ebase = ((size_t)b * N_ + n0 + 16 * w + 4 * g) * N_ + m_lo + c16;

    float4 kreg[4];
    float4 vreg[4];
    float  ereg[4][4];

    auto LOADK = [&](int m0) {
#pragma unroll
        for (int j = 0; j < 4; ++j) kreg[j] = *(const float4*)&Kg[kbase + m0 + 4 * j];
    };
    auto LOADV = [&](int m0) {
        vreg[0] = *(const float4*)&Vg[vrow + m0 + 8 * g];
        vreg[1] = *(const float4*)&Vg[vrow + m0 + 8 * g + 4];
        vreg[2] = *(const float4*)&Vg[vrow + m0 + 32 + 8 * g];
        vreg[3] = *(const float4*)&Vg[vrow + m0 + 32 + 8 * g + 4];
    };
    auto LOADE = [&](int m0) {
#pragma unroll
        for (int r = 0; r < 4; ++r)
#pragma unroll
            for (int ms = 0; ms < 4; ++ms)
                ereg[r][ms] = edge[ebase + (size_t)r * N_ + m0 + 16 * ms];
    };
    auto WRITEKT = [&]() {
#pragma unroll
        for (int j = 0; j < 4; ++j) {
            const float kf[4] = {kreg[j].x, kreg[j].y, kreg[j].z, kreg[j].w};
#pragma unroll
            for (int i = 0; i < 4; ++i)
                sKT[wv * 16 + 4 * j + i][d_ld] = (__bf16)kf[i];
        }
    };

    LOADK(0);
    LOADV(0);
    LOADE(0);
    WRITEKT();
    __syncthreads();

    for (int mt = 0; mt < MT; ++mt) {
        const int m0n = (mt < MT - 1 ? mt + 1 : mt) * 64;

        LOADK(m0n);
        bf16x8 af[2];
#pragma unroll
        for (int kc = 0; kc < 2; ++kc)
#pragma unroll
            for (int e = 0; e < 8; ++e) {
                const float* vp = (const float*)&vreg[2 * kc + (e >> 2)];
                af[kc][e] = (__bf16)vp[e & 3];
            }
        LOADV(m0n);

        f32x4 sfrag[4];
#pragma unroll
        for (int msub = 0; msub < 4; ++msub) {
            f32x4 s = (f32x4){0.f, 0.f, 0.f, 0.f};
#pragma unroll
            for (int kc = 0; kc < 2; ++kc) {
                const bf16x8 bfr = *(const bf16x8*)&sKT[16 * msub + c16][32 * kc + 8 * g];
                s = __builtin_amdgcn_mfma_f32_16x16x32_bf16(qf[kc], bfr, s, 0, 0, 0);
            }
            sfrag[msub] = s;
        }

        float rm[4];
#pragma unroll
        for (int r = 0; r < 4; ++r)
            rm[r] = fmaxf(fmaxf(sfrag[0][r], sfrag[1][r]),
                          fmaxf(sfrag[2][r], sfrag[3][r]));
        int need = 0;
#pragma unroll
        for (int r = 0; r < 4; ++r) need |= (rm[r] > M[r] + 8.0f) ? 1 : 0;

        float fr[4];
        if (__any(need)) {
#pragma unroll
            for (int mask = 1; mask < 16; mask <<= 1)
#pragma unroll
                for (int r = 0; r < 4; ++r)
                    rm[r] = fmaxf(rm[r], __shfl_xor(rm[r], mask));
#pragma unroll
            for (int r = 0; r < 4; ++r) {
                const float Mn = fmaxf(M[r], rm[r]);
                fr[r] = __expf(M[r] - Mn);
                M[r]  = Mn;
                Lr[r] *= fr[r];
            }
        } else {
#pragma unroll
            for (int r = 0; r < 4; ++r) fr[r] = 1.0f;
        }
        if (c16 == 0) {
#pragma unroll
            for (int r = 0; r < 4; ++r) sF[16 * w + 4 * g + r] = fr[r];
        }

#pragma unroll
        for (int msub = 0; msub < 4; ++msub) {
#pragma unroll
            for (int r = 0; r < 4; ++r) {
                const int nloc = 16 * w + 4 * g + r;
                const float p = __expf(sfrag[msub][r] - M[r]);
                Lr[r] += p;
                sP[nloc][16 * msub + c16] = (__bf16)(p * ereg[r][msub]);
            }
        }
        LOADE(m0n);

        __syncthreads();

#pragma unroll
        for (int nsub = 0; nsub < 4; ++nsub) {
            const float f = sF[16 * nsub + c16];
            acc[nsub] *= f;
        }
#pragma unroll
        for (int kc = 0; kc < 2; ++kc) {
#pragma unroll
            for (int nsub = 0; nsub < 4; ++nsub) {
                const bf16x8 bfr = *(const bf16x8*)&sP[16 * nsub + c16][32 * kc + 8 * g];
                acc[nsub] = __builtin_amdgcn_mfma_f32_16x16x32_bf16(af[kc], bfr, acc[nsub], 0, 0, 0);
            }
        }
        WRITEKT();

        __syncthreads();
    }

#pragma unroll
    for (int mask = 1; mask < 16; mask <<= 1)
#pragma unroll
        for (int r = 0; r < 4; ++r) Lr[r] += __shfl_xor(Lr[r], mask);
    if (c16 == 0) {
#pragma unroll
        for (int r = 0; r < 4; ++r) {
            const int nloc = 16 * w + 4 * g + r;
            ML[(size_t)pid * 128 + nloc]      = M[r];
            ML[(size_t)pid * 128 + 64 + nloc] = Lr[r];
        }
    }
#pragma unroll
    for (int nsub = 0; nsub < 4; ++nsub)
#pragma unroll
        for (int r = 0; r < 4; ++r) {
            const int dd = 16 * w + 4 * g + r;
            OP[(size_t)pid * 4096 + dd * 64 + 16 * nsub + c16] = (__bf16)acc[nsub][r];
        }
}

// ---------------------------------------------------------------------------
// Combine m-split partials.
// ---------------------------------------------------------------------------
template <int NSPLIT>
__global__ __launch_bounds__(256) void combine_kernel(
    const __bf16* __restrict__ OP, const float* __restrict__ ML,
    float* __restrict__ msg)
{
    const int nt = blockIdx.x;
    const int h  = blockIdx.y;
    const int b  = blockIdx.z;
    const int t  = threadIdx.x;
    const int d  = t & 63;
    const int seg = t >> 6;
    const int pid0 = ((b * H_ + h) * NSPLIT) * 32 + nt;

    __shared__ float sM[NSPLIT][64], sL[NSPLIT][64];
    if (t < NSPLIT * 64) {
        const int s = t >> 6, n = t & 63;
        sM[s][n] = ML[(size_t)(pid0 + s * 32) * 128 + n];
        sL[s][n] = ML[(size_t)(pid0 + s * 32) * 128 + 64 + n];
    }
    __syncthreads();

#pragma unroll
    for (int q = 0; q < 4; ++q) {
        const int c0 = seg * 16 + q * 4;
        float o[4] = {0.f, 0.f, 0.f, 0.f};
        float wgt[NSPLIT][4];
#pragma unroll
        for (int j = 0; j < 4; ++j) {
            float mx = -3.0e38f;
            for (int s = 0; s < NSPLIT; ++s) mx = fmaxf(mx, sM[s][c0 + j]);
            float den = 0.f;
            for (int s = 0; s < NSPLIT; ++s) {
                wgt[s][j] = __expf(sM[s][c0 + j] - mx);
                den += wgt[s][j] * sL[s][c0 + j];
            }
            const float inv = 1.0f / den;
            for (int s = 0; s < NSPLIT; ++s) wgt[s][j] *= inv;
        }
        for (int s = 0; s < NSPLIT; ++s) {
            const bf16x4 a = *(const bf16x4*)&OP[(size_t)(pid0 + s * 32) * 4096 + d * 64 + c0];
#pragma unroll
            for (int j = 0; j < 4; ++j) o[j] += wgt[s][j] * (float)a[j];
        }
        float4 r = {o[0], o[1], o[2], o[3]};
        *(float4*)&msg[((size_t)b * D_ + d * H_ + h) * N_ + nt * 64 + c0] = r;
    }
}

// ---------------------------------------------------------------------------
extern "C" void kernel_launch(void* const* d_in, const int* in_sizes, int n_in,
                              void* d_out, int out_size, void* d_ws, size_t ws_size,
                              hipStream_t stream) {
    const float* x      = (const float*)d_in[0];
    const float* source = (const float*)d_in[1];
    const float* edge   = (const float*)d_in[2];
    const float* Wq = (const float*)d_in[3];
    const float* bq = (const float*)d_in[4];
    const float* Wk = (const float*)d_in[5];
    const float* bk = (const float*)d_in[6];
    const float* Wv = (const float*)d_in[7];
    const float* bv = (const float*)d_in[8];
    const float* Wm = (const float*)d_in[9];
    const float* bm = (const float*)d_in[10];
    const float* W1 = (const float*)d_in[11];
    const float* b1 = (const float*)d_in[12];
    const float* W2 = (const float*)d_in[13];
    const float* b2 = (const float*)d_in[14];
    float* out = (float*)d_out;

    const size_t BDN = (size_t)B_ * D_ * N_;
    float* Qw  = (float*)d_ws;
    float* Kw  = Qw + BDN;
    float* Vw  = Kw + BDN;
    float* MSG = Vw + BDN;
    float* MES = MSG + BDN;
    float* H1  = MES + BDN;           // 2*BDN floats
    char*  tail = (char*)(H1 + 2 * BDN);
    const size_t baseBytes = (size_t)7 * BDN * 4;

    const dim3 blk(256);
    const dim3 gD(N_ / 64, D_ / 64, B_);
    const dim3 g2D(N_ / 64, 2 * D_ / 64, B_);

    // fused Q/K/V projections (MFMA)
    qkv_conv_kernel<<<dim3(N_ / 64, 12, B_), blk, 0, stream>>>(
        x, source, Wq, bq, Wk, bk, Wv, bv, Qw, Kw, Vw);

    // attention with m-split (pick max NSPLIT that fits workspace)
    auto needFor = [&](int ns) {
        const size_t pids = (size_t)ns * B_ * H_ * 32;
        return baseBytes + pids * 4096 * 2 + pids * 128 * 4;
    };
    if (ws_size >= needFor(4)) {
        const size_t pids = (size_t)4 * B_ * H_ * 32;
        __bf16* OP = (__bf16*)tail;
        float*  ML = (float*)(tail + pids * 4096 * 2);
        attn_kernel<4><<<dim3(32, H_ * 4, B_), blk, 0, stream>>>(Qw, Kw, Vw, edge, OP, ML);
        combine_kernel<4><<<dim3(32, H_, B_), blk, 0, stream>>>(OP, ML, MSG);
    } else if (ws_size >= needFor(2)) {
        const size_t pids = (size_t)2 * B_ * H_ * 32;
        __bf16* OP = (__bf16*)tail;
        float*  ML = (float*)(tail + pids * 4096 * 2);
        attn_kernel<2><<<dim3(32, H_ * 2, B_), blk, 0, stream>>>(Qw, Kw, Vw, edge, OP, ML);
        combine_kernel<2><<<dim3(32, H_, B_), blk, 0, stream>>>(OP, ML, MSG);
    } else {
        const size_t pids = (size_t)B_ * H_ * 32;
        __bf16* OP = (__bf16*)tail;
        float*  ML = (float*)(tail + pids * 4096 * 2);
        attn_kernel<1><<<dim3(32, H_, B_), blk, 0, stream>>>(Qw, Kw, Vw, edge, OP, ML);
        combine_kernel<1><<<dim3(32, H_, B_), blk, 0, stream>>>(OP, ML, MSG);
    }

    // merge heads + MLP (MFMA convs)
    mfma_conv_kernel<0><<<gD, blk, 0, stream>>>(MSG, D_, nullptr, 0, Wm, bm, MES, D_, D_);
    mfma_conv_kernel<1><<<g2D, blk, 0, stream>>>(x, D_, MES, D_, W1, b1, H1, 2 * D_, 2 * D_);
    mfma_conv_kernel<0><<<gD, blk, 0, stream>>>(H1, 2 * D_, nullptr, 0, W2, b2, out, D_, 2 * D_);
}